// Round 3
// baseline (116.511 us; speedup 1.0000x reference)
//
#include <hip/hip_runtime.h>
#include <math.h>

// Alignment (Kabsch):
//   H[b] = fx[b]^T fy[b]  (3x3, reduce over C=1024 points)
//   R[b] = (U Vh)^T == transpose of orthogonal polar factor of H[b]
//   S[b][d] = ||fy[b,:,d]|| / ||fx[b,:,d]||
//
// Kernel 1 (streaming, BW-bound): one WAVE per batch. Each lane owns 16
// consecutive points (48 floats = 12 float4), accumulates 15 partials
// (9 H + 3 sum fx^2 + 3 sum fy^2), wave shuffle-reduce, lane 0 writes to ws.
// Kernel 2 (tiny): one THREAD per batch does the f64 scaled-Newton polar
// iteration (== v @ u^T from SVD for invertible H) and writes R and S.

namespace {
constexpr int THREADS = 256;            // 4 waves = 4 batches per block
constexpr int FLOATS_PER_BATCH = 1024 * 3;
constexpr int WS_STRIDE = 16;           // floats per batch in workspace
}

__global__ __launch_bounds__(THREADS)
void reduce_kernel(const float* __restrict__ fx,
                   const float* __restrict__ fy,
                   float* __restrict__ ws)
{
    const int wave = threadIdx.x >> 6;
    const int lane = threadIdx.x & 63;
    const int b = blockIdx.x * 4 + wave;

    // lane owns points [16*lane, 16*lane+16) = float4 [12*lane, 12*lane+12)
    const float4* fx4 = reinterpret_cast<const float4*>(fx + (size_t)b * FLOATS_PER_BATCH) + 12 * lane;
    const float4* fy4 = reinterpret_cast<const float4*>(fy + (size_t)b * FLOATS_PER_BATCH) + 12 * lane;

    // v[0..8] = H[d][e] (row-major d*3+e); v[9..11]=sum fx^2; v[12..14]=sum fy^2
    float v[15];
#pragma unroll
    for (int i = 0; i < 15; ++i) v[i] = 0.0f;

#pragma unroll
    for (int c = 0; c < 4; ++c) {
        float4 a0 = fx4[3 * c + 0], a1 = fx4[3 * c + 1], a2 = fx4[3 * c + 2];
        float4 b0 = fy4[3 * c + 0], b1 = fy4[3 * c + 1], b2 = fy4[3 * c + 2];
        float X[12] = {a0.x, a0.y, a0.z, a0.w, a1.x, a1.y, a1.z, a1.w, a2.x, a2.y, a2.z, a2.w};
        float Y[12] = {b0.x, b0.y, b0.z, b0.w, b1.x, b1.y, b1.z, b1.w, b2.x, b2.y, b2.z, b2.w};
#pragma unroll
        for (int k = 0; k < 4; ++k) {
            float px0 = X[3 * k + 0], px1 = X[3 * k + 1], px2 = X[3 * k + 2];
            float py0 = Y[3 * k + 0], py1 = Y[3 * k + 1], py2 = Y[3 * k + 2];
            v[0] += px0 * py0; v[1] += px0 * py1; v[2] += px0 * py2;
            v[3] += px1 * py0; v[4] += px1 * py1; v[5] += px1 * py2;
            v[6] += px2 * py0; v[7] += px2 * py1; v[8] += px2 * py2;
            v[9]  += px0 * px0; v[10] += px1 * px1; v[11] += px2 * px2;
            v[12] += py0 * py0; v[13] += py1 * py1; v[14] += py2 * py2;
        }
    }

    // Wave-wide (64 lanes) tree reduction; no LDS, no barrier.
#pragma unroll
    for (int i = 0; i < 15; ++i) {
#pragma unroll
        for (int s = 32; s > 0; s >>= 1) v[i] += __shfl_down(v[i], s, 64);
    }

    if (lane == 0) {
        float* w = ws + (size_t)b * WS_STRIDE;
#pragma unroll
        for (int i = 0; i < 15; ++i) w[i] = v[i];
    }
}

__global__ __launch_bounds__(THREADS)
void solve_kernel(const float* __restrict__ ws,
                  float* __restrict__ out,
                  int batches)
{
    const int b = blockIdx.x * THREADS + threadIdx.x;
    if (b >= batches) return;

    const float4* w4 = reinterpret_cast<const float4*>(ws + (size_t)b * WS_STRIDE);
    float4 t0 = w4[0], t1 = w4[1], t2 = w4[2], t3 = w4[3];
    float tot[15] = {t0.x, t0.y, t0.z, t0.w, t1.x, t1.y, t1.z, t1.w,
                     t2.x, t2.y, t2.z, t2.w, t3.x, t3.y, t3.z};

    // ---- Polar decomposition of H (3x3) via scaled Newton, f64 ----
    double Q[9];
    double nf = 0.0;
#pragma unroll
    for (int i = 0; i < 9; ++i) { Q[i] = (double)tot[i]; nf += Q[i] * Q[i]; }
    double s0 = (nf > 0.0) ? 1.0 / sqrt(nf) : 1.0;
#pragma unroll
    for (int i = 0; i < 9; ++i) Q[i] *= s0;

    for (int it = 0; it < 8; ++it) {
        double C0 = Q[4] * Q[8] - Q[5] * Q[7];
        double C1 = Q[5] * Q[6] - Q[3] * Q[8];
        double C2 = Q[3] * Q[7] - Q[4] * Q[6];
        double C3 = Q[2] * Q[7] - Q[1] * Q[8];
        double C4 = Q[0] * Q[8] - Q[2] * Q[6];
        double C5 = Q[1] * Q[6] - Q[0] * Q[7];
        double C6 = Q[1] * Q[5] - Q[2] * Q[4];
        double C7 = Q[2] * Q[3] - Q[0] * Q[5];
        double C8 = Q[0] * Q[4] - Q[1] * Q[3];
        double det = Q[0] * C0 + Q[1] * C1 + Q[2] * C2;
        double ad = fabs(det);
        if (ad < 1e-300) { det = (det < 0.0) ? -1e-300 : 1e-300; ad = 1e-300; }
        double nq = Q[0]*Q[0]+Q[1]*Q[1]+Q[2]*Q[2]+Q[3]*Q[3]+Q[4]*Q[4]
                  + Q[5]*Q[5]+Q[6]*Q[6]+Q[7]*Q[7]+Q[8]*Q[8];
        double nc = C0*C0+C1*C1+C2*C2+C3*C3+C4*C4+C5*C5+C6*C6+C7*C7+C8*C8;
        double lam = sqrt(sqrt(nc) / (ad * sqrt(nq)));
        double hl = 0.5 * lam;
        double g  = 0.5 / (lam * det);
        double N0 = hl * Q[0] + g * C0;
        double N1 = hl * Q[1] + g * C1;
        double N2 = hl * Q[2] + g * C2;
        double N3 = hl * Q[3] + g * C3;
        double N4 = hl * Q[4] + g * C4;
        double N5 = hl * Q[5] + g * C5;
        double N6 = hl * Q[6] + g * C6;
        double N7 = hl * Q[7] + g * C7;
        double N8 = hl * Q[8] + g * C8;
        Q[0]=N0; Q[1]=N1; Q[2]=N2; Q[3]=N3; Q[4]=N4; Q[5]=N5; Q[6]=N6; Q[7]=N7; Q[8]=N8;
    }

    // R = Q^T (row-major [3][3])
    float* Rout = out + (size_t)b * 9;
    Rout[0] = (float)Q[0]; Rout[1] = (float)Q[3]; Rout[2] = (float)Q[6];
    Rout[3] = (float)Q[1]; Rout[4] = (float)Q[4]; Rout[5] = (float)Q[7];
    Rout[6] = (float)Q[2]; Rout[7] = (float)Q[5]; Rout[8] = (float)Q[8];

    // S[d] = sqrt(sum fy^2 / sum fx^2)
    float* Sout = out + (size_t)batches * 9 + (size_t)b * 3;
    Sout[0] = sqrtf(tot[12] / tot[9]);
    Sout[1] = sqrtf(tot[13] / tot[10]);
    Sout[2] = sqrtf(tot[14] / tot[11]);
}

extern "C" void kernel_launch(void* const* d_in, const int* in_sizes, int n_in,
                              void* d_out, int out_size, void* d_ws, size_t ws_size,
                              hipStream_t stream) {
    const float* fx = (const float*)d_in[0];
    const float* fy = (const float*)d_in[1];
    float* out = (float*)d_out;
    float* ws = (float*)d_ws;
    const int batches = in_sizes[0] / FLOATS_PER_BATCH;  // 16384

    reduce_kernel<<<batches / 4, THREADS, 0, stream>>>(fx, fy, ws);
    solve_kernel<<<(batches + THREADS - 1) / THREADS, THREADS, 0, stream>>>(ws, out, batches);
}

// Round 4
// 78.781 us; speedup vs baseline: 1.4789x; 1.4789x over previous
//
#include <hip/hip_runtime.h>
#include <math.h>

// Alignment (Kabsch):
//   H[b] = fx[b]^T fy[b]  (3x3, reduce over C=1024 points)
//   R[b] = (U Vh)^T == transpose of orthogonal polar factor of H[b]
//   S[b][d] = ||fy[b,:,d]|| / ||fx[b,:,d]||
//
// reduce_kernel: one WAVE per batch. Global loads are lane-contiguous
// (lane*16B) via global_load_lds into wave-private LDS quarters (3 KB per
// array), double-buffered with counted s_waitcnt vmcnt(6). Each lane then
// ds_read_b128's its point-aligned 12-float unit (4 points) from LDS and
// accumulates 15 partials (9 H + 3 sum fx^2 + 3 sum fy^2); wave
// shuffle-reduce; lane 0 writes 15 floats to ws.
// solve_kernel: one THREAD per batch, f64 scaled-Newton polar iteration
// (== v @ u^T from SVD for invertible H), writes R and S.

namespace {
constexpr int THREADS = 256;                 // 4 waves = 4 batches per block
constexpr int WAVES_PER_BLOCK = 4;
constexpr int FLOATS_PER_BATCH = 3072;       // 1024 points * 3
constexpr int BYTES_PER_ARR = 12288;         // 12 KB per batch per array
constexpr int QBYTES = 3072;                 // quarter: 256 points * 12 B
constexpr int LDS_PER_WAVE = 2 * 2 * QBYTES; // dbuf x {fx,fy} x 3 KB = 12 KB
constexpr int WS_STRIDE = 16;
}

__device__ inline void gload_lds16(const void* g, void* l) {
    __builtin_amdgcn_global_load_lds(
        (const __attribute__((address_space(1))) void*)g,
        (__attribute__((address_space(3))) void*)l,
        16, 0, 0);
}

__global__ __launch_bounds__(THREADS)
void reduce_kernel(const float* __restrict__ fx,
                   const float* __restrict__ fy,
                   float* __restrict__ ws)
{
    __shared__ char lds_raw[WAVES_PER_BLOCK * LDS_PER_WAVE];  // 48 KB
    const int wave = threadIdx.x >> 6;
    const int lane = threadIdx.x & 63;
    const int b = blockIdx.x * WAVES_PER_BLOCK + wave;

    char* my = lds_raw + wave * LDS_PER_WAVE;          // wave-private
    const char* gx = (const char*)fx + (size_t)b * BYTES_PER_ARR;
    const char* gy = (const char*)fy + (size_t)b * BYTES_PER_ARR;

    // Stage quarter q into buffer buf: 3 wave-loads fx + 3 fy, each 1 KB
    // contiguous (lane*16B). LDS dest is wave-uniform base (HW adds lane*16).
    auto stage = [&](int q, int buf) {
#pragma unroll
        for (int s = 0; s < 3; ++s)
            gload_lds16(gx + q * QBYTES + s * 1024 + lane * 16,
                        my + buf * (2 * QBYTES) + s * 1024);
#pragma unroll
        for (int s = 0; s < 3; ++s)
            gload_lds16(gy + q * QBYTES + s * 1024 + lane * 16,
                        my + buf * (2 * QBYTES) + QBYTES + s * 1024);
    };

    // v[0..8] = H[d][e] (row-major); v[9..11]=sum fx^2; v[12..14]=sum fy^2
    float v[15];
#pragma unroll
    for (int i = 0; i < 15; ++i) v[i] = 0.0f;

    stage(0, 0);
#pragma unroll
    for (int q = 0; q < 4; ++q) {
        const int buf = q & 1;
        if (q < 3) stage(q + 1, buf ^ 1);
        __builtin_amdgcn_sched_barrier(0);
        if (q < 3) { asm volatile("s_waitcnt vmcnt(6)" ::: "memory"); }
        else       { asm volatile("s_waitcnt vmcnt(0)" ::: "memory"); }
        __builtin_amdgcn_sched_barrier(0);

        // Lane owns 4 points = 12 floats = 48 B of this quarter.
        const float4* X4 = reinterpret_cast<const float4*>(my + buf * (2 * QBYTES) + 48 * lane);
        const float4* Y4 = reinterpret_cast<const float4*>(my + buf * (2 * QBYTES) + QBYTES + 48 * lane);
        float4 a0 = X4[0], a1 = X4[1], a2 = X4[2];
        float4 b0 = Y4[0], b1 = Y4[1], b2 = Y4[2];
        float X[12] = {a0.x, a0.y, a0.z, a0.w, a1.x, a1.y, a1.z, a1.w, a2.x, a2.y, a2.z, a2.w};
        float Y[12] = {b0.x, b0.y, b0.z, b0.w, b1.x, b1.y, b1.z, b1.w, b2.x, b2.y, b2.z, b2.w};
#pragma unroll
        for (int k = 0; k < 4; ++k) {
            float px0 = X[3 * k + 0], px1 = X[3 * k + 1], px2 = X[3 * k + 2];
            float py0 = Y[3 * k + 0], py1 = Y[3 * k + 1], py2 = Y[3 * k + 2];
            v[0] += px0 * py0; v[1] += px0 * py1; v[2] += px0 * py2;
            v[3] += px1 * py0; v[4] += px1 * py1; v[5] += px1 * py2;
            v[6] += px2 * py0; v[7] += px2 * py1; v[8] += px2 * py2;
            v[9]  += px0 * px0; v[10] += px1 * px1; v[11] += px2 * px2;
            v[12] += py0 * py0; v[13] += py1 * py1; v[14] += py2 * py2;
        }
    }

    // Wave-wide (64 lanes) tree reduction; no LDS, no barrier.
#pragma unroll
    for (int i = 0; i < 15; ++i) {
#pragma unroll
        for (int s = 32; s > 0; s >>= 1) v[i] += __shfl_down(v[i], s, 64);
    }

    if (lane == 0) {
        float* w = ws + (size_t)b * WS_STRIDE;
#pragma unroll
        for (int i = 0; i < 15; ++i) w[i] = v[i];
    }
}

__global__ __launch_bounds__(THREADS)
void solve_kernel(const float* __restrict__ ws,
                  float* __restrict__ out,
                  int batches)
{
    const int b = blockIdx.x * THREADS + threadIdx.x;
    if (b >= batches) return;

    const float4* w4 = reinterpret_cast<const float4*>(ws + (size_t)b * WS_STRIDE);
    float4 t0 = w4[0], t1 = w4[1], t2 = w4[2], t3 = w4[3];
    float tot[15] = {t0.x, t0.y, t0.z, t0.w, t1.x, t1.y, t1.z, t1.w,
                     t2.x, t2.y, t2.z, t2.w, t3.x, t3.y, t3.z};

    // ---- Polar decomposition of H (3x3) via scaled Newton, f64 ----
    double Q[9];
    double nf = 0.0;
#pragma unroll
    for (int i = 0; i < 9; ++i) { Q[i] = (double)tot[i]; nf += Q[i] * Q[i]; }
    double s0 = (nf > 0.0) ? 1.0 / sqrt(nf) : 1.0;
#pragma unroll
    for (int i = 0; i < 9; ++i) Q[i] *= s0;

    for (int it = 0; it < 8; ++it) {
        double C0 = Q[4] * Q[8] - Q[5] * Q[7];
        double C1 = Q[5] * Q[6] - Q[3] * Q[8];
        double C2 = Q[3] * Q[7] - Q[4] * Q[6];
        double C3 = Q[2] * Q[7] - Q[1] * Q[8];
        double C4 = Q[0] * Q[8] - Q[2] * Q[6];
        double C5 = Q[1] * Q[6] - Q[0] * Q[7];
        double C6 = Q[1] * Q[5] - Q[2] * Q[4];
        double C7 = Q[2] * Q[3] - Q[0] * Q[5];
        double C8 = Q[0] * Q[4] - Q[1] * Q[3];
        double det = Q[0] * C0 + Q[1] * C1 + Q[2] * C2;
        double ad = fabs(det);
        if (ad < 1e-300) { det = (det < 0.0) ? -1e-300 : 1e-300; ad = 1e-300; }
        double nq = Q[0]*Q[0]+Q[1]*Q[1]+Q[2]*Q[2]+Q[3]*Q[3]+Q[4]*Q[4]
                  + Q[5]*Q[5]+Q[6]*Q[6]+Q[7]*Q[7]+Q[8]*Q[8];
        double nc = C0*C0+C1*C1+C2*C2+C3*C3+C4*C4+C5*C5+C6*C6+C7*C7+C8*C8;
        double lam = sqrt(sqrt(nc) / (ad * sqrt(nq)));
        double hl = 0.5 * lam;
        double g  = 0.5 / (lam * det);
        double N0 = hl * Q[0] + g * C0;
        double N1 = hl * Q[1] + g * C1;
        double N2 = hl * Q[2] + g * C2;
        double N3 = hl * Q[3] + g * C3;
        double N4 = hl * Q[4] + g * C4;
        double N5 = hl * Q[5] + g * C5;
        double N6 = hl * Q[6] + g * C6;
        double N7 = hl * Q[7] + g * C7;
        double N8 = hl * Q[8] + g * C8;
        Q[0]=N0; Q[1]=N1; Q[2]=N2; Q[3]=N3; Q[4]=N4; Q[5]=N5; Q[6]=N6; Q[7]=N7; Q[8]=N8;
    }

    // R = Q^T (row-major [3][3])
    float* Rout = out + (size_t)b * 9;
    Rout[0] = (float)Q[0]; Rout[1] = (float)Q[3]; Rout[2] = (float)Q[6];
    Rout[3] = (float)Q[1]; Rout[4] = (float)Q[4]; Rout[5] = (float)Q[7];
    Rout[6] = (float)Q[2]; Rout[7] = (float)Q[5]; Rout[8] = (float)Q[8];

    // S[d] = sqrt(sum fy^2 / sum fx^2)
    float* Sout = out + (size_t)batches * 9 + (size_t)b * 3;
    Sout[0] = sqrtf(tot[12] / tot[9]);
    Sout[1] = sqrtf(tot[13] / tot[10]);
    Sout[2] = sqrtf(tot[14] / tot[11]);
}

extern "C" void kernel_launch(void* const* d_in, const int* in_sizes, int n_in,
                              void* d_out, int out_size, void* d_ws, size_t ws_size,
                              hipStream_t stream) {
    const float* fx = (const float*)d_in[0];
    const float* fy = (const float*)d_in[1];
    float* out = (float*)d_out;
    float* ws = (float*)d_ws;
    const int batches = in_sizes[0] / FLOATS_PER_BATCH;  // 16384

    reduce_kernel<<<batches / WAVES_PER_BLOCK, THREADS, 0, stream>>>(fx, fy, ws);
    solve_kernel<<<(batches + THREADS - 1) / THREADS, THREADS, 0, stream>>>(ws, out, batches);
}